// Round 5
// baseline (227.641 us; speedup 1.0000x reference)
//
#include <hip/hip_runtime.h>

#define D 1024      // in_features
#define E 64        // num experts
#define TPB 256     // threads per block (4 waves)
#define TOKS 16     // tokens per block (one 16-row MFMA strip, shared by all waves)
#define KSW 8       // k-steps per wave (K split 4 ways across the block's waves)

typedef __attribute__((ext_vector_type(8))) short bf16x8;
typedef __attribute__((ext_vector_type(8))) unsigned short u16x8;
typedef __attribute__((ext_vector_type(4))) float f32x4;
typedef __attribute__((ext_vector_type(4))) unsigned int u32x4;

__device__ __forceinline__ unsigned short bf16_rne(float f) {
    unsigned u = __builtin_bit_cast(unsigned, f);
    u += 0x7fffu + ((u >> 16) & 1u);
    return (unsigned short)(u >> 16);
}
__device__ __forceinline__ float bf16_to_f(unsigned short h) {
    unsigned u = ((unsigned)h) << 16;
    return __builtin_bit_cast(float, u);
}
__device__ __forceinline__ unsigned cvt_pk_bf16(float a, float b) {
    // dst[15:0] = bf16_rne(a), dst[31:16] = bf16_rne(b)  (hardware RNE,
    // bit-identical to bf16_rne() for normal values)
    unsigned r;
    asm("v_cvt_pk_bf16_f32 %0, %1, %2" : "=v"(r) : "v"(a), "v"(b));
    return r;
}
__device__ __forceinline__ float lo_val(unsigned p) {
    return __builtin_bit_cast(float, p << 16);
}
__device__ __forceinline__ float hi_val(unsigned p) {
    return __builtin_bit_cast(float, p & 0xffff0000u);
}

// Named-member pipeline stages only (rule #20: runtime-indexed register
// arrays demote to scratch — round-2's VGPR_Count=32 proved it).
struct Afrag { f32x4 u, v; };
struct Bfrag { bf16x8 f0, f1, f2, f3, f4, f5, f6, f7; };

// Split 8 fp32 into bf16 hi (RNE) + bf16 lo (RNE of exact residual).
// Bitwise-identical values to the verified split_hi_lo scheme.
__device__ __forceinline__ void split8_rne(f32x4 a, f32x4 b, bf16x8& hv, bf16x8& lv) {
    unsigned h0 = cvt_pk_bf16(a[0], a[1]);
    unsigned h1 = cvt_pk_bf16(a[2], a[3]);
    unsigned h2 = cvt_pk_bf16(b[0], b[1]);
    unsigned h3 = cvt_pk_bf16(b[2], b[3]);
    unsigned l0 = cvt_pk_bf16(a[0] - lo_val(h0), a[1] - hi_val(h0));
    unsigned l1 = cvt_pk_bf16(a[2] - lo_val(h1), a[3] - hi_val(h1));
    unsigned l2 = cvt_pk_bf16(b[0] - lo_val(h2), b[1] - hi_val(h2));
    unsigned l3 = cvt_pk_bf16(b[2] - lo_val(h3), b[3] - hi_val(h3));
    hv = __builtin_bit_cast(bf16x8, (u32x4){h0, h1, h2, h3});
    lv = __builtin_bit_cast(bf16x8, (u32x4){l0, l1, l2, l3});
}

// ---------------------------------------------------------------------------
// One-time prep: split W (64x1024 fp32) into RNE hi/lo bf16, laid out in
// exact MFMA B-fragment lane order: record f = (ks*4 + nt)*2 + hl, each
// record 64 lanes x 8 bf16 (16B/lane).  Lane (n=lane&15, q=lane>>4) holds
// W[nt*16+n][ks*32 + q*8 + 0..7].  256 KB total -> d_ws.  (Unchanged, proven.)
// ---------------------------------------------------------------------------
__global__ __launch_bounds__(TPB) void router_prep(
        const float* __restrict__ W, unsigned short* __restrict__ Ws) {
    int t = blockIdx.x * TPB + threadIdx.x;  // 0..8191
    int lane = t & 63;
    int nt = (t >> 6) & 3;
    int ks = t >> 8;
    int n = lane & 15, q = lane >> 4;
    const float* src = W + (size_t)(nt * 16 + n) * D + ks * 32 + q * 8;
    u16x8 hv, lv;
#pragma unroll
    for (int j = 0; j < 8; ++j) {
        float v = src[j];
        unsigned short h = bf16_rne(v);
        hv[j] = h;
        lv[j] = bf16_rne(v - bf16_to_f(h));
    }
    size_t base = ((size_t)(ks * 8 + nt * 2) * 64 + lane) * 8;
    *(u16x8*)(Ws + base)          = hv;      // hl = 0
    *(u16x8*)(Ws + base + 64 * 8) = lv;      // hl = 1 (next record)
}

// ---------------------------------------------------------------------------
// Main, K-split for occupancy: 2048 blocks x 4 waves = 8192 waves (4x more
// than all previous designs).  Each block owns 16 tokens; wave w computes
// k-steps [8w, 8w+8) with B read DIRECTLY from L2 (prep's fragment layout,
// 16B/lane coalesced) — no LDS staging, zero barriers in the K-loop.
// fp32 partials reduced across waves in LDS in a fixed deterministic order
// ((p0+p1)+p2)+p3 + bias.  VGPR kept <=128 (single-buffered B, named regs)
// so 16 waves/CU are resident.
// ---------------------------------------------------------------------------
__global__ __launch_bounds__(TPB, 4) void router_main(
        const float* __restrict__ x, const unsigned short* __restrict__ Ws,
        const float* __restrict__ bias, float* __restrict__ out, int T) {
    __shared__ __align__(16) float part[4][TOKS][E];   // 16 KB partials
    __shared__ float ls[TOKS][E + 1];
    __shared__ float sbias[E];

    const int tid  = threadIdx.x;
    const int lane = tid & 63;
    const int wid  = tid >> 6;     // K-slice id 0..3
    const int n    = lane & 15;
    const int q    = lane >> 4;
    const int t0   = blockIdx.x * TOKS;
    const int kb   = wid * KSW;    // this wave's first k-step

    if (tid < E) sbias[tid] = bias[tid];

    const float* arow = x + (size_t)(t0 + n) * D + q * 8;
    const bf16x8* bptr = (const bf16x8*)Ws + lane;

    f32x4 c0 = {0.f, 0.f, 0.f, 0.f}, c1 = c0, c2 = c0, c3 = c0;
    bf16x8 ah, al;
    Afrag A0, A1;
    Bfrag Bt;

#define LOADA(A_, ks_) do {                                   \
        A_.u = *(const f32x4*)(arow + (ks_) * 32);            \
        A_.v = *(const f32x4*)(arow + (ks_) * 32 + 4);        \
    } while (0)

#define LOADB(ks_) do {                                       \
        const bf16x8* _p = bptr + (size_t)(ks_) * 512;        \
        Bt.f0 = _p[0];   Bt.f1 = _p[64];  Bt.f2 = _p[128];    \
        Bt.f3 = _p[192]; Bt.f4 = _p[256]; Bt.f5 = _p[320];    \
        Bt.f6 = _p[384]; Bt.f7 = _p[448];                     \
    } while (0)

#define MFMA __builtin_amdgcn_mfma_f32_16x16x32_bf16
#define COMP() do {                                           \
        c0 = MFMA(ah, Bt.f0, c0, 0, 0, 0);                    \
        c0 = MFMA(al, Bt.f0, c0, 0, 0, 0);                    \
        c0 = MFMA(ah, Bt.f1, c0, 0, 0, 0);                    \
        c1 = MFMA(ah, Bt.f2, c1, 0, 0, 0);                    \
        c1 = MFMA(al, Bt.f2, c1, 0, 0, 0);                    \
        c1 = MFMA(ah, Bt.f3, c1, 0, 0, 0);                    \
        c2 = MFMA(ah, Bt.f4, c2, 0, 0, 0);                    \
        c2 = MFMA(al, Bt.f4, c2, 0, 0, 0);                    \
        c2 = MFMA(ah, Bt.f5, c2, 0, 0, 0);                    \
        c3 = MFMA(ah, Bt.f6, c3, 0, 0, 0);                    \
        c3 = MFMA(al, Bt.f6, c3, 0, 0, 0);                    \
        c3 = MFMA(ah, Bt.f7, c3, 0, 0, 0);                    \
    } while (0)

    // A register pipeline depth 2; B issued first each step so its vmcnt
    // wait retires only B.  All clamps are compile-time after full unroll
    // (clamped refills harmlessly reload the wave's last k-step).
    LOADA(A0, kb + 0);
    LOADA(A1, kb + 1);

#pragma unroll
    for (int kk = 0; kk < KSW; kk += 2) {
        {
            LOADB(kb + kk);
            split8_rne(A0.u, A0.v, ah, al);
            const int kr = (kk + 2 < KSW) ? kk + 2 : KSW - 1;
            LOADA(A0, kb + kr);
            COMP();
        }
        {
            LOADB(kb + kk + 1);
            split8_rne(A1.u, A1.v, ah, al);
            const int kr = (kk + 3 < KSW) ? kk + 3 : KSW - 1;
            LOADA(A1, kb + kr);
            COMP();
        }
    }

    // partials to LDS: C/D layout col = lane&15 (expert base nt*16), row = q*4+r (token)
    {
        const int row = q * 4;
#define STORE_P(c_, nt_) do {                                 \
            int col = (nt_) * 16 + n;                         \
            part[wid][row + 0][col] = c_[0];                  \
            part[wid][row + 1][col] = c_[1];                  \
            part[wid][row + 2][col] = c_[2];                  \
            part[wid][row + 3][col] = c_[3];                  \
        } while (0)
        STORE_P(c0, 0); STORE_P(c1, 1); STORE_P(c2, 2); STORE_P(c3, 3);
#undef STORE_P
    }
    __syncthreads();

    // deterministic cross-wave reduce + bias: 1024 (token,expert) pairs,
    // 4 per thread, fixed order ((p0+p1)+p2)+p3 + bias
#pragma unroll
    for (int j = 0; j < 4; ++j) {
        int idx = tid + j * TPB;
        int tok = idx >> 6, e = idx & 63;
        float s = ((part[0][tok][e] + part[1][tok][e]) + part[2][tok][e])
                  + part[3][tok][e];
        ls[tok][e] = s + sbias[e];
    }
    __syncthreads();

    if (tid < TOKS) {
        float m1 = -3.4e38f, m2 = -3.4e38f;
        int i1 = 0, i2 = 0;
        for (int e = 0; e < E; ++e) {
            float v = ls[tid][e];
            if (v > m1) { m2 = m1; i2 = i1; m1 = v; i1 = e; }
            else if (v > m2) { m2 = v; i2 = e; }
        }
        float Z = 0.f;
        for (int e = 0; e < E; ++e) Z += __expf(ls[tid][e] - m1);
        float inv = 1.f / Z;
        int gt = t0 + tid;
        out[(size_t)gt * 2]     = inv;                  // exp(m1-m1)/Z
        out[(size_t)gt * 2 + 1] = __expf(m2 - m1) * inv;
        float* oi = out + (size_t)T * 2;
        oi[(size_t)gt * 2]     = (float)i1;             // indices as floats
        oi[(size_t)gt * 2 + 1] = (float)i2;
    }
}

extern "C" void kernel_launch(void* const* d_in, const int* in_sizes, int n_in,
                              void* d_out, int out_size, void* d_ws, size_t ws_size,
                              hipStream_t stream) {
    const float* x = (const float*)d_in[0];
    const float* W = (const float*)d_in[1];
    const float* b = (const float*)d_in[2];
    float* out = (float*)d_out;
    unsigned short* Ws = (unsigned short*)d_ws;   // needs 256 KB
    int T = in_sizes[0] / D;                      // 32768 tokens
    hipLaunchKernelGGL(router_prep, dim3(32), dim3(TPB), 0, stream, W, Ws);
    hipLaunchKernelGGL(router_main, dim3(T / TOKS), dim3(TPB), 0, stream,
                       x, Ws, b, out, T);
}